// Round 3
// baseline (316.438 us; speedup 1.0000x reference)
//
#include <hip/hip_runtime.h>
#include <math.h>

// QuantumNeuralNetwork: 12-qubit, 16-layer RY+CNOT-ring state-vector sim.
// Round 3: round-2 structure (one state per 128-thread block, 32 complex
// amps/lane) but state held in ext_vector_type SSA values -- round 2's
// float[32] allocas were never promoted (VGPR_Count=64 proves it) and spilled
// ~350 MB/dispatch of scratch traffic. Also fuses the NLL loss into the sim
// epilogue via atomicAdd (kills the 57 us serialized qnn_loss launch).
// Layer structure (all RY gates commute):
//   L1 layout: lane t owns amp bits 11..5, reg r1 = amp bits 4..0
//     -> q7..q11 register-local; q5,q6 via quad-perm DPP (amp bits 6,5 = t1,t0)
//   LDS trip 1 -> L2 layout: reg r2 = amp bits 11..7, lane owns bits 6..0
//     -> q0..q4 register-local
//   LDS trip 2 -> back to L1 FUSED with the CNOT-ring permutation G (linear).
// Swizzle f(x)=x^(x>>6): all 4 LDS phases have rank-5 bank projection -> 2-way
// aliasing only (free, m136).

#define DIM     4096
#define NLAYERS 16
#define BATCH   2048
#define NCLASS  5

typedef float v32f __attribute__((ext_vector_type(32)));

// Composite CNOT-ring gather: psi_new[i] = psi_old[gperm(i)]. GF(2)-linear.
__host__ __device__ constexpr unsigned gperm(unsigned i) {
  for (int q = 11; q >= 0; --q) {
    const unsigned cbit = 1u << (11 - q);
    const unsigned tbit = 1u << (11 - ((q + 1) % 12));
    if (i & cbit) i ^= tbit;
  }
  return i;
}
__host__ __device__ constexpr unsigned swz(unsigned x) { return x ^ (x >> 6); }

// quad_perm DPP permute (VALU, no LDS): CTRL 0x4E = xor-2, 0xB1 = xor-1
template<int CTRL>
__device__ __forceinline__ float dppf(float x) {
  return __int_as_float(__builtin_amdgcn_update_dpp(
      0, __float_as_int(x), CTRL, 0xF, 0xF, true));
}

__global__ __launch_bounds__(128, 4)
void qnn_sim(const float* __restrict__ zr, const float* __restrict__ zi,
             const float* __restrict__ thetas, const int* __restrict__ y,
             float* __restrict__ out) {
  __shared__ float buf[DIM];  // 16 KB: one component of the state
  const int b = blockIdx.x;
  const int t = threadIdx.x;  // 0..127

  // Layer-invariant LDS slot bases (float indices), f(x)=x^(x>>6):
  // W1 : slot = f((t<<5)|r1)          = wb1 ^ r1
  // R1/W2: slot = f((r2<<7)|t)        = rb1 ^ ((r2<<7)|(r2<<1))
  // R2 : slot = f(G((t<<5)|r1))       = rb2 ^ swz(gperm(r1))   [G,f linear]
  const int wb1 = ((t << 5) ^ (t >> 1));
  const int rb1 = (t ^ (t >> 6));
  const int Xt  = ((t << 5) ^ (t << 4)) & 0xFFF;  // G(t<<5)
  const int rb2 = (Xt ^ (Xt >> 6));

  v32f re, im;
  {
    const float* zrb = zr + (size_t)b * DIM + (t << 5);
    const float* zib = zi + (size_t)b * DIM + (t << 5);
#pragma unroll
    for (int k = 0; k < 8; ++k) {
      const float4 v = ((const float4*)zrb)[k];
      const float4 u = ((const float4*)zib)[k];
      re[4*k+0]=v.x; re[4*k+1]=v.y; re[4*k+2]=v.z; re[4*k+3]=v.w;
      im[4*k+0]=u.x; im[4*k+1]=u.y; im[4*k+2]=u.z; im[4*k+3]=u.w;
    }
  }

#pragma unroll 1
  for (int l = 0; l < NLAYERS; ++l) {
    const float* th = thetas + l * 12;

    // ---- L1 register gates: q7..q11  (pair masks r1: 16,8,4,2,1) ----
#pragma unroll
    for (int g = 0; g < 5; ++g) {
      const float a = 0.5f * th[7 + g];
      const float c = __cosf(a), s = __sinf(a);
      const int m = 16 >> g;
#pragma unroll
      for (int r = 0; r < 32; ++r) {
        if (r & m) continue;
        const int rp = r | m;
        const float a0 = re[r], a1 = re[rp];
        re[r]  = c * a0 - s * a1;
        re[rp] = s * a0 + c * a1;
        const float b0 = im[r], b1 = im[rp];
        im[r]  = c * b0 - s * b1;
        im[rp] = s * b0 + c * b1;
      }
    }

    // ---- DPP gates: q5 (amp bit6 = t1, xor-2) ; q6 (amp bit5 = t0, xor-1)
    {
      const float a5 = 0.5f * th[5];
      const float c5 = __cosf(a5), s5 = __sinf(a5);
      const float ss5 = (t & 2) ? s5 : -s5;
#pragma unroll
      for (int r = 0; r < 32; ++r) {
        re[r] = __builtin_fmaf(c5, re[r], ss5 * dppf<0x4E>(re[r]));
        im[r] = __builtin_fmaf(c5, im[r], ss5 * dppf<0x4E>(im[r]));
      }
      const float a6 = 0.5f * th[6];
      const float c6 = __cosf(a6), s6 = __sinf(a6);
      const float ss6 = (t & 1) ? s6 : -s6;
#pragma unroll
      for (int r = 0; r < 32; ++r) {
        re[r] = __builtin_fmaf(c6, re[r], ss6 * dppf<0xB1>(re[r]));
        im[r] = __builtin_fmaf(c6, im[r], ss6 * dppf<0xB1>(im[r]));
      }
    }

    // ---- trip 1: L1 -> L2 (per component) ----
    __syncthreads();  // prev phase's reads done
#pragma unroll
    for (int r = 0; r < 32; ++r) buf[wb1 ^ r] = re[r];
    __syncthreads();
#pragma unroll
    for (int r = 0; r < 32; ++r) re[r] = buf[rb1 ^ ((r << 7) | (r << 1))];
    __syncthreads();
#pragma unroll
    for (int r = 0; r < 32; ++r) buf[wb1 ^ r] = im[r];
    __syncthreads();
#pragma unroll
    for (int r = 0; r < 32; ++r) im[r] = buf[rb1 ^ ((r << 7) | (r << 1))];

    // ---- L2 register gates: q0..q4 (pair masks r2: 16,8,4,2,1) ----
#pragma unroll
    for (int g = 0; g < 5; ++g) {
      const float a = 0.5f * th[g];
      const float c = __cosf(a), s = __sinf(a);
      const int m = 16 >> g;
#pragma unroll
      for (int r = 0; r < 32; ++r) {
        if (r & m) continue;
        const int rp = r | m;
        const float a0 = re[r], a1 = re[rp];
        re[r]  = c * a0 - s * a1;
        re[rp] = s * a0 + c * a1;
        const float b0 = im[r], b1 = im[rp];
        im[r]  = c * b0 - s * b1;
        im[rp] = s * b0 + c * b1;
      }
    }

    // ---- trip 2: L2 -> L1 fused with CNOT-ring gather ----
    __syncthreads();
#pragma unroll
    for (int r = 0; r < 32; ++r) buf[rb1 ^ ((r << 7) | (r << 1))] = re[r];
    __syncthreads();
#pragma unroll
    for (int r = 0; r < 32; ++r) re[r] = buf[rb2 ^ (int)swz(gperm((unsigned)r))];
    __syncthreads();
#pragma unroll
    for (int r = 0; r < 32; ++r) buf[rb1 ^ ((r << 7) | (r << 1))] = im[r];
    __syncthreads();
#pragma unroll
    for (int r = 0; r < 32; ++r) im[r] = buf[rb2 ^ (int)swz(gperm((unsigned)r))];
  }

  // ---- Z expectations: wire w sign = amp bit (11-w) = t bit (6-w) ----
  float P = 0.f;
#pragma unroll
  for (int r = 0; r < 32; ++r) P += re[r] * re[r] + im[r] * im[r];
  float e[5];
#pragma unroll
  for (int w = 0; w < 5; ++w) e[w] = ((t >> (6 - w)) & 1) ? -P : P;
#pragma unroll
  for (int off = 32; off >= 1; off >>= 1) {
#pragma unroll
    for (int w = 0; w < 5; ++w) e[w] += __shfl_xor(e[w], off);
  }
  __syncthreads();  // protect buf (last R2-im reads done)
  if ((t & 63) == 0) {
#pragma unroll
    for (int w = 0; w < 5; ++w) buf[(t >> 6) * 8 + w] = e[w];
  }
  __syncthreads();
  if (t == 0) {
    float o[5];
#pragma unroll
    for (int w = 0; w < 5; ++w) o[w] = buf[w] + buf[8 + w];
    float* op = out + 1 + (size_t)b * NCLASS;
#pragma unroll
    for (int w = 0; w < 5; ++w) op[w] = o[w];
    // fused NLL: loss contribution = (logsumexp(o) - o[y]) / BATCH
    float m = fmaxf(fmaxf(fmaxf(o[0], o[1]), fmaxf(o[2], o[3])), o[4]);
    const float sum = expf(o[0] - m) + expf(o[1] - m) + expf(o[2] - m) +
                      expf(o[3] - m) + expf(o[4] - m);
    const float nll = (m + logf(sum)) - o[y[b]];
    atomicAdd(out, nll * (1.0f / BATCH));
  }
}

extern "C" void kernel_launch(void* const* d_in, const int* in_sizes, int n_in,
                              void* d_out, int out_size, void* d_ws, size_t ws_size,
                              hipStream_t stream) {
  const float* zr = (const float*)d_in[0];
  const float* zi = (const float*)d_in[1];
  const float* th = (const float*)d_in[2];
  const int*   y  = (const int*)d_in[3];
  float* out = (float*)d_out;
  hipMemsetAsync(out, 0, sizeof(float), stream);  // zero loss accumulator
  qnn_sim<<<BATCH, 128, 0, stream>>>(zr, zi, th, y, out);
}

// Round 4
// 312.260 us; speedup vs baseline: 1.0134x; 1.0134x over previous
//
#include <hip/hip_runtime.h>
#include <math.h>

// QuantumNeuralNetwork: 12-qubit, 16-layer RY+CNOT-ring state-vector sim.
// Round 4: same dataflow as rounds 2/3 (one state per 128-thread block, 32
// complex amps/lane, two LDS re-layouts per layer, CNOT-ring fused into
// trip 2) but the state is now 64 EXPLICIT SCALAR floats (re0..re31,
// im0..im31) with preprocessor-unrolled gate/LDS code.
// Why: round 2's float[32] never got SROA-promoted (alloca -> scratch);
// round 3's ext_vector_type(32) became a 32-reg contiguous tuple the
// allocator spilled whole (VGPR_Count==64==state size, 450 MB scratch
// traffic in both). Named scalars are guaranteed SSA -> discrete VGPRs.
// Layer structure (all RY gates in a layer commute):
//   L1 layout: lane t owns amp bits 11..5, reg r1 = amp bits 4..0
//     -> q7..q11 register-local; q5,q6 via quad-perm DPP (amp bits 6,5=t1,t0)
//   LDS trip 1 -> L2 layout: reg r2 = amp bits 11..7, lane owns bits 6..0
//     -> q0..q4 register-local
//   LDS trip 2 -> back to L1 FUSED with CNOT-ring permutation G (GF(2)-linear)
// Swizzle f(x)=x^(x>>6): all 4 LDS phases have rank-5 bank projections ->
// only 2-way bank aliasing (free on gfx950, m136).

#define DIM     4096
#define NLAYERS 16
#define BATCH   2048
#define NCLASS  5

// Composite CNOT-ring gather: psi_new[i] = psi_old[gperm(i)]. GF(2)-linear.
__host__ __device__ constexpr unsigned gperm(unsigned i) {
  for (int q = 11; q >= 0; --q) {
    const unsigned cbit = 1u << (11 - q);
    const unsigned tbit = 1u << (11 - ((q + 1) % 12));
    if (i & cbit) i ^= tbit;
  }
  return i;
}
__host__ __device__ constexpr unsigned swz(unsigned x) { return x ^ (x >> 6); }

// quad_perm DPP permute (VALU, no LDS): CTRL 0x4E = xor-2, 0xB1 = xor-1
template<int CTRL>
__device__ __forceinline__ float dppf(float x) {
  return __int_as_float(__builtin_amdgcn_update_dpp(
      0, __float_as_int(x), CTRL, 0xF, 0xF, true));
}

#define FOR32(M) M(0) M(1) M(2) M(3) M(4) M(5) M(6) M(7) M(8) M(9) M(10) \
  M(11) M(12) M(13) M(14) M(15) M(16) M(17) M(18) M(19) M(20) M(21) M(22) \
  M(23) M(24) M(25) M(26) M(27) M(28) M(29) M(30) M(31)

// one RY pair-rotation on registers p0,p1 (uses locals c,s in scope)
#define ROT(p0, p1) {                                        \
    const float A0 = re##p0, A1 = re##p1;                    \
    re##p0 = __builtin_fmaf(c, A0, -s * A1);                 \
    re##p1 = __builtin_fmaf(s, A0,  c * A1);                 \
    const float B0 = im##p0, B1 = im##p1;                    \
    im##p0 = __builtin_fmaf(c, B0, -s * B1);                 \
    im##p1 = __builtin_fmaf(s, B0,  c * B1); }

#define GM16 ROT(0,16) ROT(1,17) ROT(2,18) ROT(3,19) ROT(4,20) ROT(5,21) \
  ROT(6,22) ROT(7,23) ROT(8,24) ROT(9,25) ROT(10,26) ROT(11,27) ROT(12,28) \
  ROT(13,29) ROT(14,30) ROT(15,31)
#define GM8 ROT(0,8) ROT(1,9) ROT(2,10) ROT(3,11) ROT(4,12) ROT(5,13) \
  ROT(6,14) ROT(7,15) ROT(16,24) ROT(17,25) ROT(18,26) ROT(19,27) ROT(20,28) \
  ROT(21,29) ROT(22,30) ROT(23,31)
#define GM4 ROT(0,4) ROT(1,5) ROT(2,6) ROT(3,7) ROT(8,12) ROT(9,13) \
  ROT(10,14) ROT(11,15) ROT(16,20) ROT(17,21) ROT(18,22) ROT(19,23) \
  ROT(24,28) ROT(25,29) ROT(26,30) ROT(27,31)
#define GM2 ROT(0,2) ROT(1,3) ROT(4,6) ROT(5,7) ROT(8,10) ROT(9,11) \
  ROT(12,14) ROT(13,15) ROT(16,18) ROT(17,19) ROT(20,22) ROT(21,23) \
  ROT(24,26) ROT(25,27) ROT(28,30) ROT(29,31)
#define GM1 ROT(0,1) ROT(2,3) ROT(4,5) ROT(6,7) ROT(8,9) ROT(10,11) \
  ROT(12,13) ROT(14,15) ROT(16,17) ROT(18,19) ROT(20,21) ROT(22,23) \
  ROT(24,25) ROT(26,27) ROT(28,29) ROT(30,31)

__global__ __launch_bounds__(128, 4)
void qnn_sim(const float* __restrict__ zr, const float* __restrict__ zi,
             const float* __restrict__ thetas, const int* __restrict__ y,
             float* __restrict__ out) {
  __shared__ float buf[DIM];  // 16 KB: one component of the state
  const int b = blockIdx.x;
  const int t = threadIdx.x;  // 0..127

  // Layer-invariant LDS slot bases (float indices), f(x)=x^(x>>6):
  // W1  : slot = f((t<<5)|r1)    = wb1 ^ r1
  // R1/W2: slot = f((r2<<7)|t)   = rb1 ^ ((r2<<7)|(r2<<1))
  // R2  : slot = f(G((t<<5)|r1)) = rb2 ^ swz(gperm(r1))   [G,f linear]
  const int wb1 = ((t << 5) ^ (t >> 1));
  const int rb1 = (t ^ (t >> 6));
  const int Xt  = ((t << 5) ^ (t << 4)) & 0xFFF;  // G(t<<5)
  const int rb2 = (Xt ^ (Xt >> 6));

  float re0,re1,re2,re3,re4,re5,re6,re7,re8,re9,re10,re11,re12,re13,re14,re15,
        re16,re17,re18,re19,re20,re21,re22,re23,re24,re25,re26,re27,re28,re29,
        re30,re31;
  float im0,im1,im2,im3,im4,im5,im6,im7,im8,im9,im10,im11,im12,im13,im14,im15,
        im16,im17,im18,im19,im20,im21,im22,im23,im24,im25,im26,im27,im28,im29,
        im30,im31;
  {
    const float4* zr4 = (const float4*)(zr + (size_t)b * DIM + (t << 5));
    const float4* zi4 = (const float4*)(zi + (size_t)b * DIM + (t << 5));
    float4 v;
    v = zr4[0]; re0 =v.x; re1 =v.y; re2 =v.z; re3 =v.w;
    v = zr4[1]; re4 =v.x; re5 =v.y; re6 =v.z; re7 =v.w;
    v = zr4[2]; re8 =v.x; re9 =v.y; re10=v.z; re11=v.w;
    v = zr4[3]; re12=v.x; re13=v.y; re14=v.z; re15=v.w;
    v = zr4[4]; re16=v.x; re17=v.y; re18=v.z; re19=v.w;
    v = zr4[5]; re20=v.x; re21=v.y; re22=v.z; re23=v.w;
    v = zr4[6]; re24=v.x; re25=v.y; re26=v.z; re27=v.w;
    v = zr4[7]; re28=v.x; re29=v.y; re30=v.z; re31=v.w;
    v = zi4[0]; im0 =v.x; im1 =v.y; im2 =v.z; im3 =v.w;
    v = zi4[1]; im4 =v.x; im5 =v.y; im6 =v.z; im7 =v.w;
    v = zi4[2]; im8 =v.x; im9 =v.y; im10=v.z; im11=v.w;
    v = zi4[3]; im12=v.x; im13=v.y; im14=v.z; im15=v.w;
    v = zi4[4]; im16=v.x; im17=v.y; im18=v.z; im19=v.w;
    v = zi4[5]; im20=v.x; im21=v.y; im22=v.z; im23=v.w;
    v = zi4[6]; im24=v.x; im25=v.y; im26=v.z; im27=v.w;
    v = zi4[7]; im28=v.x; im29=v.y; im30=v.z; im31=v.w;
  }

#pragma unroll 1
  for (int l = 0; l < NLAYERS; ++l) {
    const float* th = thetas + l * 12;

    // ---- L1 register gates: q7..q11 (pair masks 16,8,4,2,1) ----
    { const float a = 0.5f * th[7];  const float c = __cosf(a), s = __sinf(a); GM16 }
    { const float a = 0.5f * th[8];  const float c = __cosf(a), s = __sinf(a); GM8  }
    { const float a = 0.5f * th[9];  const float c = __cosf(a), s = __sinf(a); GM4  }
    { const float a = 0.5f * th[10]; const float c = __cosf(a), s = __sinf(a); GM2  }
    { const float a = 0.5f * th[11]; const float c = __cosf(a), s = __sinf(a); GM1  }

    // ---- DPP gates: q5 (amp bit6 = t1, xor-2) ; q6 (amp bit5 = t0, xor-1)
    {
      const float a5 = 0.5f * th[5];
      const float c5 = __cosf(a5), s5 = __sinf(a5);
      const float ss5 = (t & 2) ? s5 : -s5;
#define DPP5(i) \
      re##i = __builtin_fmaf(c5, re##i, ss5 * dppf<0x4E>(re##i)); \
      im##i = __builtin_fmaf(c5, im##i, ss5 * dppf<0x4E>(im##i));
      FOR32(DPP5)
#undef DPP5
      const float a6 = 0.5f * th[6];
      const float c6 = __cosf(a6), s6 = __sinf(a6);
      const float ss6 = (t & 1) ? s6 : -s6;
#define DPP6(i) \
      re##i = __builtin_fmaf(c6, re##i, ss6 * dppf<0xB1>(re##i)); \
      im##i = __builtin_fmaf(c6, im##i, ss6 * dppf<0xB1>(im##i));
      FOR32(DPP6)
#undef DPP6
    }

    // ---- trip 1: L1 -> L2 (per component) ----
    __syncthreads();  // prev phase's reads done
#define W1R(i) buf[wb1 ^ i] = re##i;
#define R1R(i) re##i = buf[rb1 ^ ((i << 7) | (i << 1))];
#define W1I(i) buf[wb1 ^ i] = im##i;
#define R1I(i) im##i = buf[rb1 ^ ((i << 7) | (i << 1))];
    FOR32(W1R)
    __syncthreads();
    FOR32(R1R)
    __syncthreads();
    FOR32(W1I)
    __syncthreads();
    FOR32(R1I)
#undef W1R
#undef R1R
#undef W1I
#undef R1I

    // ---- L2 register gates: q0..q4 (pair masks 16,8,4,2,1) ----
    { const float a = 0.5f * th[0]; const float c = __cosf(a), s = __sinf(a); GM16 }
    { const float a = 0.5f * th[1]; const float c = __cosf(a), s = __sinf(a); GM8  }
    { const float a = 0.5f * th[2]; const float c = __cosf(a), s = __sinf(a); GM4  }
    { const float a = 0.5f * th[3]; const float c = __cosf(a), s = __sinf(a); GM2  }
    { const float a = 0.5f * th[4]; const float c = __cosf(a), s = __sinf(a); GM1  }

    // ---- trip 2: L2 -> L1 fused with CNOT-ring gather ----
    __syncthreads();
#define W2R(i) buf[rb1 ^ ((i << 7) | (i << 1))] = re##i;
#define R2R(i) re##i = buf[rb2 ^ (int)swz(gperm((unsigned)i))];
#define W2I(i) buf[rb1 ^ ((i << 7) | (i << 1))] = im##i;
#define R2I(i) im##i = buf[rb2 ^ (int)swz(gperm((unsigned)i))];
    FOR32(W2R)
    __syncthreads();
    FOR32(R2R)
    __syncthreads();
    FOR32(W2I)
    __syncthreads();
    FOR32(R2I)
#undef W2R
#undef R2R
#undef W2I
#undef R2I
  }

  // ---- Z expectations: wire w sign = amp bit (11-w) = t bit (6-w) ----
  float P = 0.f;
#define ACC(i) P += re##i * re##i + im##i * im##i;
  FOR32(ACC)
#undef ACC
  float e0 = ((t >> 6) & 1) ? -P : P;
  float e1 = ((t >> 5) & 1) ? -P : P;
  float e2 = ((t >> 4) & 1) ? -P : P;
  float e3 = ((t >> 3) & 1) ? -P : P;
  float e4 = ((t >> 2) & 1) ? -P : P;
#pragma unroll
  for (int off = 32; off >= 1; off >>= 1) {
    e0 += __shfl_xor(e0, off);
    e1 += __shfl_xor(e1, off);
    e2 += __shfl_xor(e2, off);
    e3 += __shfl_xor(e3, off);
    e4 += __shfl_xor(e4, off);
  }
  __syncthreads();  // protect buf (last R2I reads done)
  if ((t & 63) == 0) {
    const int w8 = (t >> 6) * 8;
    buf[w8 + 0] = e0; buf[w8 + 1] = e1; buf[w8 + 2] = e2;
    buf[w8 + 3] = e3; buf[w8 + 4] = e4;
  }
  __syncthreads();
  if (t == 0) {
    const float o0 = buf[0] + buf[8];
    const float o1 = buf[1] + buf[9];
    const float o2 = buf[2] + buf[10];
    const float o3 = buf[3] + buf[11];
    const float o4 = buf[4] + buf[12];
    float* op = out + 1 + (size_t)b * NCLASS;
    op[0] = o0; op[1] = o1; op[2] = o2; op[3] = o3; op[4] = o4;
    // fused NLL: loss contribution = (logsumexp(o) - o[y]) / BATCH
    const float m = fmaxf(fmaxf(fmaxf(o0, o1), fmaxf(o2, o3)), o4);
    const float sum = expf(o0 - m) + expf(o1 - m) + expf(o2 - m) +
                      expf(o3 - m) + expf(o4 - m);
    const int yb = y[b];
    const float oy = (yb == 0) ? o0 : (yb == 1) ? o1 : (yb == 2) ? o2
                   : (yb == 3) ? o3 : o4;
    const float nll = (m + logf(sum)) - oy;
    atomicAdd(out, nll * (1.0f / BATCH));
  }
}

extern "C" void kernel_launch(void* const* d_in, const int* in_sizes, int n_in,
                              void* d_out, int out_size, void* d_ws, size_t ws_size,
                              hipStream_t stream) {
  const float* zr = (const float*)d_in[0];
  const float* zi = (const float*)d_in[1];
  const float* th = (const float*)d_in[2];
  const int*   y  = (const int*)d_in[3];
  float* out = (float*)d_out;
  hipMemsetAsync(out, 0, sizeof(float), stream);  // zero loss accumulator
  qnn_sim<<<BATCH, 128, 0, stream>>>(zr, zi, th, y, out);
}